// Round 1
// baseline (51707.147 us; speedup 1.0000x reference)
//
#include <hip/hip_runtime.h>
#include <math.h>

#define H 2048
#define SEQ 4096
#define NOUT 1000
#define NBLK 64          // recurrence blocks
#define RPB 32           // rows per block
#define RPW 4            // rows per wave
#define THREADS_REC 512  // 8 waves

// ---------------------------------------------------------------- init
__global__ void zero_cnt_kernel(int* cnt) {
    int i = blockIdx.x * blockDim.x + threadIdx.x;
    if (i < SEQ) cnt[i] = 0;
}

__global__ void copy_hidden_kernel(const float* __restrict__ hidden, float* __restrict__ out) {
    int i = blockIdx.x * blockDim.x + threadIdx.x;
    if (i < H) out[i] = hidden[i];
}

// ------------------------------------------- GEMM  C = A * Bt^T + bias
// A: MxK row-major, Bt: NxK row-major (both K-contiguous), C: MxN.
// M % 64 == 0 assumed; N bounds-checked; K % 16 == 0 assumed.
#define TS 64
#define KK 16
#define LP 21   // padded LDS stride (bank-conflict mitigation)
__global__ __launch_bounds__(256) void gemm_abt_f32(
    const float* __restrict__ A, const float* __restrict__ Bt,
    const float* __restrict__ bias, float* __restrict__ C,
    int M, int N, int K)
{
    __shared__ float As[TS][LP];
    __shared__ float Bs[TS][LP];
    const int tid = threadIdx.x;
    const int tx = tid & 15, ty = tid >> 4;
    const int bm = blockIdx.y * TS, bn = blockIdx.x * TS;
    const int lrow = tid >> 2;            // 0..63
    const int lcol = (tid & 3) << 2;      // 0,4,8,12
    float acc[4][4] = {};
    for (int k0 = 0; k0 < K; k0 += KK) {
        float4 av, bv;
        av = *(const float4*)(A + (size_t)(bm + lrow) * K + k0 + lcol);
        int brow = bn + lrow;
        if (brow < N) bv = *(const float4*)(Bt + (size_t)brow * K + k0 + lcol);
        else { bv.x = bv.y = bv.z = bv.w = 0.f; }
        __syncthreads();
        As[lrow][lcol+0] = av.x; As[lrow][lcol+1] = av.y;
        As[lrow][lcol+2] = av.z; As[lrow][lcol+3] = av.w;
        Bs[lrow][lcol+0] = bv.x; Bs[lrow][lcol+1] = bv.y;
        Bs[lrow][lcol+2] = bv.z; Bs[lrow][lcol+3] = bv.w;
        __syncthreads();
        #pragma unroll
        for (int k = 0; k < KK; ++k) {
            float ar[4], br[4];
            #pragma unroll
            for (int i = 0; i < 4; ++i) ar[i] = As[ty*4+i][k];
            #pragma unroll
            for (int j = 0; j < 4; ++j) br[j] = Bs[tx*4+j][k];
            #pragma unroll
            for (int i = 0; i < 4; ++i)
                #pragma unroll
                for (int j = 0; j < 4; ++j)
                    acc[i][j] = fmaf(ar[i], br[j], acc[i][j]);
        }
    }
    #pragma unroll
    for (int i = 0; i < 4; ++i) {
        int row = bm + ty*4 + i;
        #pragma unroll
        for (int j = 0; j < 4; ++j) {
            int col = bn + tx*4 + j;
            if (col < N) C[(size_t)row * N + col] = acc[i][j] + bias[col];
        }
    }
}

// ------------------------------------------------- persistent RNN scan
// 64 blocks x 512 threads. Block owns 32 rows of W_hh in registers
// (wave w: rows rbase..rbase+3; lane l: cols {4l+256k+e}).
// Per step: LDS GEMV -> wave butterfly reduce -> tanh -> publish slice to
// global double buffer -> device counter barrier -> reload h into LDS.
__global__ __launch_bounds__(THREADS_REC, 2) void rnn_scan_kernel(
    const float* __restrict__ xp, const float* __restrict__ Whh,
    const float* __restrict__ bhh, const float* __restrict__ h0,
    float* __restrict__ hs, float* gbuf, int* cnt)
{
    __shared__ float h_s[H];
    const int tid  = threadIdx.x;
    const int lane = tid & 63;
    const int wid  = tid >> 6;
    const int bid  = blockIdx.x;
    const int rbase = bid * RPB + wid * RPW;

    // --- load weights into registers (coalesced float4, one-time 16 MiB) ---
    float w[RPW][32];
    #pragma unroll
    for (int r = 0; r < RPW; ++r) {
        const float* wp = Whh + (size_t)(rbase + r) * H + (lane << 2);
        #pragma unroll
        for (int k = 0; k < 8; ++k) {
            float4 wv = *(const float4*)(wp + (k << 8));
            w[r][k*4+0] = wv.x; w[r][k*4+1] = wv.y;
            w[r][k*4+2] = wv.z; w[r][k*4+3] = wv.w;
        }
    }
    float bb = (lane < RPW) ? bhh[rbase + lane] : 0.f;

    for (int i = tid; i < H; i += THREADS_REC) h_s[i] = h0[i];
    __syncthreads();

    float xv = (lane < RPW) ? xp[rbase + lane] : 0.f;

    for (int t = 0; t < SEQ; ++t) {
        // prefetch next step's xp (hidden under GEMV+barrier)
        float nx = 0.f;
        if (lane < RPW && t + 1 < SEQ) nx = xp[(size_t)(t + 1) * H + rbase + lane];

        // --- GEMV: 8x ds_read_b128, 128 FMA per lane ---
        float a0 = 0.f, a1 = 0.f, a2 = 0.f, a3 = 0.f;
        #pragma unroll
        for (int k = 0; k < 8; ++k) {
            float4 hv = *(const float4*)&h_s[(lane << 2) + (k << 8)];
            a0 = fmaf(w[0][k*4+0], hv.x, a0); a0 = fmaf(w[0][k*4+1], hv.y, a0);
            a0 = fmaf(w[0][k*4+2], hv.z, a0); a0 = fmaf(w[0][k*4+3], hv.w, a0);
            a1 = fmaf(w[1][k*4+0], hv.x, a1); a1 = fmaf(w[1][k*4+1], hv.y, a1);
            a1 = fmaf(w[1][k*4+2], hv.z, a1); a1 = fmaf(w[1][k*4+3], hv.w, a1);
            a2 = fmaf(w[2][k*4+0], hv.x, a2); a2 = fmaf(w[2][k*4+1], hv.y, a2);
            a2 = fmaf(w[2][k*4+2], hv.z, a2); a2 = fmaf(w[2][k*4+3], hv.w, a2);
            a3 = fmaf(w[3][k*4+0], hv.x, a3); a3 = fmaf(w[3][k*4+1], hv.y, a3);
            a3 = fmaf(w[3][k*4+2], hv.z, a3); a3 = fmaf(w[3][k*4+3], hv.w, a3);
        }
        // --- butterfly reduce across the 64 lanes (all lanes end with sums) ---
        #pragma unroll
        for (int off = 32; off >= 1; off >>= 1) {
            a0 += __shfl_xor(a0, off);
            a1 += __shfl_xor(a1, off);
            a2 += __shfl_xor(a2, off);
            a3 += __shfl_xor(a3, off);
        }

        float* wb = gbuf + (((t + 1) & 1) << 11);   // double buffer
        if (lane < RPW) {
            float av = (lane == 0) ? a0 : (lane == 1) ? a1 : (lane == 2) ? a2 : a3;
            float hval = tanhf(av + xv + bb);
            __hip_atomic_store(&wb[rbase + lane], hval, __ATOMIC_RELAXED, __HIP_MEMORY_SCOPE_AGENT);
            if (t >= SEQ - H)
                hs[(size_t)(t - (SEQ - H)) * H + rbase + lane] = hval;
            __threadfence();   // agent-scope: slice visible before arrival
        }
        __syncthreads();

        if (t + 1 < SEQ) {
            if (tid == 0) {
                __hip_atomic_fetch_add(&cnt[t], 1, __ATOMIC_RELEASE, __HIP_MEMORY_SCOPE_AGENT);
                while (__hip_atomic_load(&cnt[t], __ATOMIC_ACQUIRE, __HIP_MEMORY_SCOPE_AGENT) < NBLK)
                    __builtin_amdgcn_s_sleep(2);
            }
            __syncthreads();
            // --- reload h_{t+1} into LDS (coherent agent-scope loads) ---
            #pragma unroll
            for (int s = 0; s < 4; ++s) {
                int i = tid + s * THREADS_REC;
                h_s[i] = __hip_atomic_load(&wb[i], __ATOMIC_RELAXED, __HIP_MEMORY_SCOPE_AGENT);
            }
            __syncthreads();
        }
        xv = nx;
    }
}

// ---------------------------------------------------------------- launch
extern "C" void kernel_launch(void* const* d_in, const int* in_sizes, int n_in,
                              void* d_out, int out_size, void* d_ws, size_t ws_size,
                              hipStream_t stream) {
    const float* input  = (const float*)d_in[0];
    const float* hidden = (const float*)d_in[1];
    const float* W_ih   = (const float*)d_in[2];
    const float* b_ih   = (const float*)d_in[3];
    const float* W_hh   = (const float*)d_in[4];
    const float* b_hh   = (const float*)d_in[5];
    const float* W_out  = (const float*)d_in[6];
    const float* b_out  = (const float*)d_in[7];
    float* out = (float*)d_out;

    // ws layout: xp[SEQ*H] | hs[H*H] | gbuf[2*H] | cnt[SEQ]   (~48 MiB)
    char* ws = (char*)d_ws;
    float* xp   = (float*)ws;
    float* hs   = (float*)(ws + (size_t)SEQ * H * 4);
    float* gbuf = (float*)(ws + (size_t)SEQ * H * 4 + (size_t)H * H * 4);
    int*   cnt  = (int*)  (ws + (size_t)SEQ * H * 4 + (size_t)H * H * 4 + 2 * H * 4);

    zero_cnt_kernel<<<dim3(16), dim3(256), 0, stream>>>(cnt);

    // phase 1: xp = input @ W_ih^T + b_ih   (M=4096, N=2048, K=2048)
    gemm_abt_f32<<<dim3(H / TS, SEQ / TS), dim3(256), 0, stream>>>(
        input, W_ih, b_ih, xp, SEQ, H, H);

    // phase 2: sequential scan, persistent weights
    rnn_scan_kernel<<<dim3(NBLK), dim3(THREADS_REC), 0, stream>>>(
        xp, W_hh, b_hh, hidden, hs, gbuf, cnt);

    // phase 3: out = hs @ W_out^T + b_out   (M=2048, N=1000, K=2048)
    gemm_abt_f32<<<dim3((NOUT + TS - 1) / TS, H / TS), dim3(256), 0, stream>>>(
        hs, W_out, b_out, out, H, NOUT, H);

    // output tuple tail: unchanged hidden state
    copy_hidden_kernel<<<dim3(8), dim3(256), 0, stream>>>(hidden, out + (size_t)H * NOUT);
}

// Round 2
// 19733.038 us; speedup vs baseline: 2.6203x; 2.6203x over previous
//
#include <hip/hip_runtime.h>
#include <math.h>

#define H 2048
#define SEQ 4096
#define NOUT 1000
#define NBLK 64          // recurrence blocks
#define RPB 32           // rows per block
#define RPW 4            // rows per wave
#define THREADS_REC 512  // 8 waves

// ---------------------------------------------------------------- init
__global__ void zero_flags_kernel(int* flags) {
    int i = blockIdx.x * blockDim.x + threadIdx.x;
    if (i < NBLK) flags[i] = 0;
}

__global__ void copy_hidden_kernel(const float* __restrict__ hidden, float* __restrict__ out) {
    int i = blockIdx.x * blockDim.x + threadIdx.x;
    if (i < H) out[i] = hidden[i];
}

// ------------------------------------------- GEMM  C = A * Bt^T + bias
// A: MxK row-major, Bt: NxK row-major (both K-contiguous), C: MxN.
// M % 64 == 0 assumed; N bounds-checked; K % 16 == 0 assumed.
#define TS 64
#define KK 16
#define LP 21   // padded LDS stride (bank-conflict mitigation)
__global__ __launch_bounds__(256) void gemm_abt_f32(
    const float* __restrict__ A, const float* __restrict__ Bt,
    const float* __restrict__ bias, float* __restrict__ C,
    int M, int N, int K)
{
    __shared__ float As[TS][LP];
    __shared__ float Bs[TS][LP];
    const int tid = threadIdx.x;
    const int tx = tid & 15, ty = tid >> 4;
    const int bm = blockIdx.y * TS, bn = blockIdx.x * TS;
    const int lrow = tid >> 2;            // 0..63
    const int lcol = (tid & 3) << 2;      // 0,4,8,12
    float acc[4][4] = {};
    for (int k0 = 0; k0 < K; k0 += KK) {
        float4 av, bv;
        av = *(const float4*)(A + (size_t)(bm + lrow) * K + k0 + lcol);
        int brow = bn + lrow;
        if (brow < N) bv = *(const float4*)(Bt + (size_t)brow * K + k0 + lcol);
        else { bv.x = bv.y = bv.z = bv.w = 0.f; }
        __syncthreads();
        As[lrow][lcol+0] = av.x; As[lrow][lcol+1] = av.y;
        As[lrow][lcol+2] = av.z; As[lrow][lcol+3] = av.w;
        Bs[lrow][lcol+0] = bv.x; Bs[lrow][lcol+1] = bv.y;
        Bs[lrow][lcol+2] = bv.z; Bs[lrow][lcol+3] = bv.w;
        __syncthreads();
        #pragma unroll
        for (int k = 0; k < KK; ++k) {
            float ar[4], br[4];
            #pragma unroll
            for (int i = 0; i < 4; ++i) ar[i] = As[ty*4+i][k];
            #pragma unroll
            for (int j = 0; j < 4; ++j) br[j] = Bs[tx*4+j][k];
            #pragma unroll
            for (int i = 0; i < 4; ++i)
                #pragma unroll
                for (int j = 0; j < 4; ++j)
                    acc[i][j] = fmaf(ar[i], br[j], acc[i][j]);
        }
    }
    #pragma unroll
    for (int i = 0; i < 4; ++i) {
        int row = bm + ty*4 + i;
        #pragma unroll
        for (int j = 0; j < 4; ++j) {
            int col = bn + tx*4 + j;
            if (col < N) C[(size_t)row * N + col] = acc[i][j] + bias[col];
        }
    }
}

// ------------------------------------------------- persistent RNN scan
// 64 blocks x 512 threads. Block owns 32 rows of W_hh in registers
// (wave w: rows rbase..rbase+3; lane l: cols {4l+256k+e}), pinned via asm.
// Per step: LDS GEMV -> wave butterfly reduce -> tanh -> publish slice
// (relaxed agent atomic stores -> LLC, no fences anywhere) -> per-block
// monotonic flag -> wave0 polls all 64 flags -> reload h into LDS.
__global__ __launch_bounds__(THREADS_REC, 2) void rnn_scan_kernel(
    const float* __restrict__ xp, const float* __restrict__ Whh,
    const float* __restrict__ bhh, const float* __restrict__ h0,
    float* __restrict__ hs, float* gbuf, int* flags)
{
    __shared__ float h_s[H];
    const int tid  = threadIdx.x;
    const int lane = tid & 63;
    const int wid  = tid >> 6;
    const int bid  = blockIdx.x;
    const int rbase = bid * RPB + wid * RPW;

    // --- load weights into registers (coalesced float4, one-time 16 MiB) ---
    float w[RPW][32];
    #pragma unroll
    for (int r = 0; r < RPW; ++r) {
        const float* wp = Whh + (size_t)(rbase + r) * H + (lane << 2);
        #pragma unroll
        for (int k = 0; k < 8; ++k) {
            float4 wv = *(const float4*)(wp + (k << 8));
            w[r][k*4+0] = wv.x; w[r][k*4+1] = wv.y;
            w[r][k*4+2] = wv.z; w[r][k*4+3] = wv.w;
        }
    }
    // pin weights in VGPRs: opaque asm def prevents rematerialization/sinking
    #pragma unroll
    for (int r = 0; r < RPW; ++r)
        #pragma unroll
        for (int j = 0; j < 32; ++j)
            asm volatile("" : "+v"(w[r][j]));

    float bb = (lane < RPW) ? bhh[rbase + lane] : 0.f;

    for (int i = tid; i < H; i += THREADS_REC) h_s[i] = h0[i];
    __syncthreads();

    float xv = (lane < RPW) ? xp[rbase + lane] : 0.f;

    for (int t = 0; t < SEQ; ++t) {
        // prefetch next step's xp (hidden under GEMV)
        float nx = 0.f;
        if (lane < RPW && t + 1 < SEQ) nx = xp[(size_t)(t + 1) * H + rbase + lane];

        // --- GEMV: 8x ds_read_b128, 128 FMA per lane ---
        float a0 = 0.f, a1 = 0.f, a2 = 0.f, a3 = 0.f;
        #pragma unroll
        for (int k = 0; k < 8; ++k) {
            float4 hv = *(const float4*)&h_s[(lane << 2) + (k << 8)];
            a0 = fmaf(w[0][k*4+0], hv.x, a0); a0 = fmaf(w[0][k*4+1], hv.y, a0);
            a0 = fmaf(w[0][k*4+2], hv.z, a0); a0 = fmaf(w[0][k*4+3], hv.w, a0);
            a1 = fmaf(w[1][k*4+0], hv.x, a1); a1 = fmaf(w[1][k*4+1], hv.y, a1);
            a1 = fmaf(w[1][k*4+2], hv.z, a1); a1 = fmaf(w[1][k*4+3], hv.w, a1);
            a2 = fmaf(w[2][k*4+0], hv.x, a2); a2 = fmaf(w[2][k*4+1], hv.y, a2);
            a2 = fmaf(w[2][k*4+2], hv.z, a2); a2 = fmaf(w[2][k*4+3], hv.w, a2);
            a3 = fmaf(w[3][k*4+0], hv.x, a3); a3 = fmaf(w[3][k*4+1], hv.y, a3);
            a3 = fmaf(w[3][k*4+2], hv.z, a3); a3 = fmaf(w[3][k*4+3], hv.w, a3);
        }
        // --- butterfly reduce across the 64 lanes ---
        #pragma unroll
        for (int off = 32; off >= 1; off >>= 1) {
            a0 += __shfl_xor(a0, off);
            a1 += __shfl_xor(a1, off);
            a2 += __shfl_xor(a2, off);
            a3 += __shfl_xor(a3, off);
        }

        float* wb = gbuf + (((t + 1) & 1) << 11);   // double buffer
        if (lane < RPW) {
            float av = (lane == 0) ? a0 : (lane == 1) ? a1 : (lane == 2) ? a2 : a3;
            float hval = tanhf(av + xv + bb);
            // direct-to-LLC store (sc1): coherent across XCDs, no fence needed
            __hip_atomic_store(&wb[rbase + lane], hval, __ATOMIC_RELAXED, __HIP_MEMORY_SCOPE_AGENT);
            if (t >= SEQ - H)
                hs[(size_t)(t - (SEQ - H)) * H + rbase + lane] = hval;
        }
        // __syncthreads drains each wave's vmcnt before the barrier ->
        // all 32 slice stores are LLC-visible before the flag goes up.
        __syncthreads();

        if (t + 1 < SEQ) {
            if (tid == 0)
                __hip_atomic_store(&flags[bid], t + 1, __ATOMIC_RELAXED, __HIP_MEMORY_SCOPE_AGENT);
            if (wid == 0) {
                // lane l watches block l's flag; monotonic values, no reset
                for (;;) {
                    int f = __hip_atomic_load(&flags[lane], __ATOMIC_RELAXED, __HIP_MEMORY_SCOPE_AGENT);
                    if (__all(f >= t + 1)) break;
                }
            }
            __syncthreads();
            // --- reload h_{t+1} into LDS (sc1 loads from LLC, bypass L1/L2) ---
            const float* rb = wb;
            #pragma unroll
            for (int s = 0; s < 4; ++s) {
                int i = tid + (s << 9);
                h_s[i] = __hip_atomic_load(&rb[i], __ATOMIC_RELAXED, __HIP_MEMORY_SCOPE_AGENT);
            }
            __syncthreads();
        }
        xv = nx;
    }
}

// ---------------------------------------------------------------- launch
extern "C" void kernel_launch(void* const* d_in, const int* in_sizes, int n_in,
                              void* d_out, int out_size, void* d_ws, size_t ws_size,
                              hipStream_t stream) {
    const float* input  = (const float*)d_in[0];
    const float* hidden = (const float*)d_in[1];
    const float* W_ih   = (const float*)d_in[2];
    const float* b_ih   = (const float*)d_in[3];
    const float* W_hh   = (const float*)d_in[4];
    const float* b_hh   = (const float*)d_in[5];
    const float* W_out  = (const float*)d_in[6];
    const float* b_out  = (const float*)d_in[7];
    float* out = (float*)d_out;

    // ws layout: xp[SEQ*H] | hs[H*H] | gbuf[2*H] | flags[NBLK]
    char* ws = (char*)d_ws;
    float* xp    = (float*)ws;
    float* hs    = (float*)(ws + (size_t)SEQ * H * 4);
    float* gbuf  = (float*)(ws + (size_t)SEQ * H * 4 + (size_t)H * H * 4);
    int*   flags = (int*)  (ws + (size_t)SEQ * H * 4 + (size_t)H * H * 4 + 2 * H * 4);

    zero_flags_kernel<<<dim3(1), dim3(64), 0, stream>>>(flags);

    // phase 1: xp = input @ W_ih^T + b_ih   (M=4096, N=2048, K=2048)
    gemm_abt_f32<<<dim3(H / TS, SEQ / TS), dim3(256), 0, stream>>>(
        input, W_ih, b_ih, xp, SEQ, H, H);

    // phase 2: sequential scan, persistent weights
    rnn_scan_kernel<<<dim3(NBLK), dim3(THREADS_REC), 0, stream>>>(
        xp, W_hh, b_hh, hidden, hs, gbuf, flags);

    // phase 3: out = hs @ W_out^T + b_out   (M=2048, N=1000, K=2048)
    gemm_abt_f32<<<dim3((NOUT + TS - 1) / TS, H / TS), dim3(256), 0, stream>>>(
        hs, W_out, b_out, out, H, NOUT, H);

    // output tuple tail: unchanged hidden state
    copy_hidden_kernel<<<dim3(8), dim3(256), 0, stream>>>(hidden, out + (size_t)H * NOUT);
}

// Round 5
// 13886.612 us; speedup vs baseline: 3.7235x; 1.4210x over previous
//
#include <hip/hip_runtime.h>
#include <math.h>

#define H 2048
#define SEQ 4096
#define NOUT 1000
#define NBLK 64          // recurrence blocks
#define RPB 32           // rows per block
#define RPW 4            // rows per wave
#define THREADS_REC 512  // 8 waves
#define FPAD 32          // flags padded to 128B (one LLC line each)

// ---------------------------------------------------------------- init
// buf0 <- h0 (so the scan always reads gbuf), flags <- 0
__global__ void init_kernel(const float* __restrict__ h0, float* __restrict__ gbuf,
                            int* __restrict__ flags) {
    int i = blockIdx.x * blockDim.x + threadIdx.x;
    if (i < H) gbuf[i] = h0[i];
    if (i < NBLK * FPAD) flags[i] = 0;
}

__global__ void copy_hidden_kernel(const float* __restrict__ hidden, float* __restrict__ out) {
    int i = blockIdx.x * blockDim.x + threadIdx.x;
    if (i < H) out[i] = hidden[i];
}

// ------------------------------------------- GEMM  C = A * Bt^T + bias
#define TS 64
#define KK 16
#define LP 21
__global__ __launch_bounds__(256) void gemm_abt_f32(
    const float* __restrict__ A, const float* __restrict__ Bt,
    const float* __restrict__ bias, float* __restrict__ C,
    int M, int N, int K)
{
    __shared__ float As[TS][LP];
    __shared__ float Bs[TS][LP];
    const int tid = threadIdx.x;
    const int tx = tid & 15, ty = tid >> 4;
    const int bm = blockIdx.y * TS, bn = blockIdx.x * TS;
    const int lrow = tid >> 2;
    const int lcol = (tid & 3) << 2;
    float acc[4][4] = {};
    for (int k0 = 0; k0 < K; k0 += KK) {
        float4 av, bv;
        av = *(const float4*)(A + (size_t)(bm + lrow) * K + k0 + lcol);
        int brow = bn + lrow;
        if (brow < N) bv = *(const float4*)(Bt + (size_t)brow * K + k0 + lcol);
        else { bv.x = bv.y = bv.z = bv.w = 0.f; }
        __syncthreads();
        As[lrow][lcol+0] = av.x; As[lrow][lcol+1] = av.y;
        As[lrow][lcol+2] = av.z; As[lrow][lcol+3] = av.w;
        Bs[lrow][lcol+0] = bv.x; Bs[lrow][lcol+1] = bv.y;
        Bs[lrow][lcol+2] = bv.z; Bs[lrow][lcol+3] = bv.w;
        __syncthreads();
        #pragma unroll
        for (int k = 0; k < KK; ++k) {
            float ar[4], br[4];
            #pragma unroll
            for (int i = 0; i < 4; ++i) ar[i] = As[ty*4+i][k];
            #pragma unroll
            for (int j = 0; j < 4; ++j) br[j] = Bs[tx*4+j][k];
            #pragma unroll
            for (int i = 0; i < 4; ++i)
                #pragma unroll
                for (int j = 0; j < 4; ++j)
                    acc[i][j] = fmaf(ar[i], br[j], acc[i][j]);
        }
    }
    #pragma unroll
    for (int i = 0; i < 4; ++i) {
        int row = bm + ty*4 + i;
        #pragma unroll
        for (int j = 0; j < 4; ++j) {
            int col = bn + tx*4 + j;
            if (col < N) C[(size_t)row * N + col] = acc[i][j] + bias[col];
        }
    }
}

// ------------------------------------------------- persistent RNN scan
// 64 blocks x 512 threads. Block owns 32 rows of W_hh in registers.
// Per step (ONE __syncthreads total):
//   coherent dwordx4 loads of h_t -> GEMV regs (no LDS)
//   FMA + butterfly reduce + tanh
//   relaxed agent atomic store of slice -> LLC double buffer
//   syncthreads (drains all waves' stores) ; tid0 raises padded flag
//   every wave polls all 64 padded flags (lane l watches flag l)
__global__ __launch_bounds__(THREADS_REC, 2) void rnn_scan_kernel(
    const float* __restrict__ xp, const float* __restrict__ Whh,
    const float* __restrict__ bhh,
    float* __restrict__ hs, float* gbuf, int* flags)
{
    const int tid  = threadIdx.x;
    const int lane = tid & 63;
    const int wid  = tid >> 6;
    const int bid  = blockIdx.x;
    const int rbase = bid * RPB + wid * RPW;

    // --- load weights into registers (one-time 16 MiB, coalesced) ---
    float w[RPW][32];
    #pragma unroll
    for (int r = 0; r < RPW; ++r) {
        const float* wp = Whh + (size_t)(rbase + r) * H + (lane << 2);
        #pragma unroll
        for (int k = 0; k < 8; ++k) {
            float4 wv = *(const float4*)(wp + (k << 8));
            w[r][k*4+0] = wv.x; w[r][k*4+1] = wv.y;
            w[r][k*4+2] = wv.z; w[r][k*4+3] = wv.w;
        }
    }
    #pragma unroll
    for (int r = 0; r < RPW; ++r)
        #pragma unroll
        for (int j = 0; j < 32; ++j)
            asm volatile("" : "+v"(w[r][j]));

    float bb = (lane < RPW) ? bhh[rbase + lane] : 0.f;
    float xv = (lane < RPW) ? xp[rbase + lane] : 0.f;

    for (int t = 0; t < SEQ; ++t) {
        // prefetch next step's xp (independent, hides under h loads)
        float nx = 0.f;
        if (lane < RPW && t + 1 < SEQ) nx = xp[(size_t)(t + 1) * H + rbase + lane];

        // --- coherent vector loads of h_t straight into GEMV registers ---
        const float* rb = gbuf + ((t & 1) << 11);
        const float* p  = rb + (lane << 2);
        float4 h0v, h1v, h2v, h3v, h4v, h5v, h6v, h7v;
        asm volatile("global_load_dwordx4 %0, %1, off sc0 sc1" : "=v"(h0v) : "v"(p));
        asm volatile("global_load_dwordx4 %0, %1, off sc0 sc1" : "=v"(h1v) : "v"(p + 256));
        asm volatile("global_load_dwordx4 %0, %1, off sc0 sc1" : "=v"(h2v) : "v"(p + 512));
        asm volatile("global_load_dwordx4 %0, %1, off sc0 sc1" : "=v"(h3v) : "v"(p + 768));
        asm volatile("global_load_dwordx4 %0, %1, off sc0 sc1" : "=v"(h4v) : "v"(p + 1024));
        asm volatile("global_load_dwordx4 %0, %1, off sc0 sc1" : "=v"(h5v) : "v"(p + 1280));
        asm volatile("global_load_dwordx4 %0, %1, off sc0 sc1" : "=v"(h6v) : "v"(p + 1536));
        asm volatile("global_load_dwordx4 %0, %1, off sc0 sc1" : "=v"(h7v) : "v"(p + 1792));
        // rule #18: plain waitcnt + sched_barrier keeps consumers below the wait
        asm volatile("s_waitcnt vmcnt(0)" ::: "memory");
        __builtin_amdgcn_sched_barrier(0);

        float a0 = 0.f, a1 = 0.f, a2 = 0.f, a3 = 0.f;
        #define GEMV_STEP(k, hv)                                               \
            a0 = fmaf(w[0][k*4+0], hv.x, a0); a0 = fmaf(w[0][k*4+1], hv.y, a0);\
            a0 = fmaf(w[0][k*4+2], hv.z, a0); a0 = fmaf(w[0][k*4+3], hv.w, a0);\
            a1 = fmaf(w[1][k*4+0], hv.x, a1); a1 = fmaf(w[1][k*4+1], hv.y, a1);\
            a1 = fmaf(w[1][k*4+2], hv.z, a1); a1 = fmaf(w[1][k*4+3], hv.w, a1);\
            a2 = fmaf(w[2][k*4+0], hv.x, a2); a2 = fmaf(w[2][k*4+1], hv.y, a2);\
            a2 = fmaf(w[2][k*4+2], hv.z, a2); a2 = fmaf(w[2][k*4+3], hv.w, a2);\
            a3 = fmaf(w[3][k*4+0], hv.x, a3); a3 = fmaf(w[3][k*4+1], hv.y, a3);\
            a3 = fmaf(w[3][k*4+2], hv.z, a3); a3 = fmaf(w[3][k*4+3], hv.w, a3);
        GEMV_STEP(0, h0v) GEMV_STEP(1, h1v) GEMV_STEP(2, h2v) GEMV_STEP(3, h3v)
        GEMV_STEP(4, h4v) GEMV_STEP(5, h5v) GEMV_STEP(6, h6v) GEMV_STEP(7, h7v)
        #undef GEMV_STEP

        #pragma unroll
        for (int off = 32; off >= 1; off >>= 1) {
            a0 += __shfl_xor(a0, off);
            a1 += __shfl_xor(a1, off);
            a2 += __shfl_xor(a2, off);
            a3 += __shfl_xor(a3, off);
        }

        float* wb = gbuf + (((t + 1) & 1) << 11);
        if (lane < RPW) {
            float av = (lane == 0) ? a0 : (lane == 1) ? a1 : (lane == 2) ? a2 : a3;
            float hval = tanhf(av + xv + bb);
            __hip_atomic_store(&wb[rbase + lane], hval, __ATOMIC_RELAXED, __HIP_MEMORY_SCOPE_AGENT);
            if (t >= SEQ - H)
                hs[(size_t)(t - (SEQ - H)) * H + rbase + lane] = hval;
        }
        // drains every wave's vmcnt -> all 32 slice stores LLC-visible
        __syncthreads();

        if (t + 1 < SEQ) {
            if (tid == 0)
                __hip_atomic_store(&flags[bid * FPAD], t + 1, __ATOMIC_RELAXED, __HIP_MEMORY_SCOPE_AGENT);
            // every wave independently confirms all 64 flags (padded lines)
            for (;;) {
                int f = __hip_atomic_load(&flags[lane * FPAD], __ATOMIC_RELAXED, __HIP_MEMORY_SCOPE_AGENT);
                if (__all(f >= t + 1)) break;
            }
        }
        xv = nx;
    }
}

// ---------------------------------------------------------------- launch
extern "C" void kernel_launch(void* const* d_in, const int* in_sizes, int n_in,
                              void* d_out, int out_size, void* d_ws, size_t ws_size,
                              hipStream_t stream) {
    const float* input  = (const float*)d_in[0];
    const float* hidden = (const float*)d_in[1];
    const float* W_ih   = (const float*)d_in[2];
    const float* b_ih   = (const float*)d_in[3];
    const float* W_hh   = (const float*)d_in[4];
    const float* b_hh   = (const float*)d_in[5];
    const float* W_out  = (const float*)d_in[6];
    const float* b_out  = (const float*)d_in[7];
    float* out = (float*)d_out;

    // ws layout: xp[SEQ*H] | hs[H*H] | gbuf[2*H] | flags[NBLK*FPAD]
    char* ws = (char*)d_ws;
    float* xp    = (float*)ws;
    float* hs    = (float*)(ws + (size_t)SEQ * H * 4);
    float* gbuf  = (float*)(ws + (size_t)SEQ * H * 4 + (size_t)H * H * 4);
    int*   flags = (int*)  (ws + (size_t)SEQ * H * 4 + (size_t)H * H * 4 + 2 * H * 4);

    init_kernel<<<dim3(8), dim3(256), 0, stream>>>(hidden, gbuf, flags);

    // phase 1: xp = input @ W_ih^T + b_ih
    gemm_abt_f32<<<dim3(H / TS, SEQ / TS), dim3(256), 0, stream>>>(
        input, W_ih, b_ih, xp, SEQ, H, H);

    // phase 2: sequential scan, persistent weights
    rnn_scan_kernel<<<dim3(NBLK), dim3(THREADS_REC), 0, stream>>>(
        xp, W_hh, b_hh, hs, gbuf, flags);

    // phase 3: out = hs @ W_out^T + b_out
    gemm_abt_f32<<<dim3((NOUT + TS - 1) / TS, H / TS), dim3(256), 0, stream>>>(
        hs, W_out, b_out, out, H, NOUT, H);

    // output tuple tail: unchanged hidden state
    copy_hidden_kernel<<<dim3(8), dim3(256), 0, stream>>>(hidden, out + (size_t)H * NOUT);
}